// Round 8
// baseline (298.205 us; speedup 1.0000x reference)
//
#include <hip/hip_runtime.h>
#include <hip/hip_fp16.h>

typedef _Float16 half8 __attribute__((ext_vector_type(8)));
typedef float floatx4 __attribute__((ext_vector_type(4)));

#define AS1 __attribute__((address_space(1)))
#define AS3 __attribute__((address_space(3)))

// workspace layout (halfs):
//   [0, WTOT)                  W fragments, contiguous layout:
//       ((nt*16+kt)*12 + mat)*2048 + wn*512 + lane*8
//       mat 0..5 = hi {ir,hr,iz,hz,in,hn}, mat 6..11 = lo (same order)
//   [APERM_OFF, +APERM_HALFS)  x/h hi/lo fragment-ordered (per mt,kt:
//       Xh|Xl|Hh|Hl x 4096 halfs)
// legacy old-layout offsets kept for the fallback path only.
#define WTOT ((size_t)(8 * 16 * 12 * 2048))
#define APERM_OFF WTOT
#define APERM_HALFS ((size_t)128 * 16 * 4 * 4096)
#define WLO_OFF (6 * 512 * 512)                 // fallback (old layout)
#define WMAT_STRIDE ((size_t)(8 * 16 * 2048))   // fallback (old layout)

__device__ __forceinline__ void async_lds16(const void* g, void* l) {
  __builtin_amdgcn_global_load_lds((const AS1 void*)g, (AS3 void*)l, 16, 0, 0);
}

// ---------------------------------------------------------------------------
// prep: blocks 0..1023 -> x/h fp32 to fragment-ordered f16 hi/lo (aperm).
//   Block = (mt, kt-pair): reads 128 rows x 64 cols (256B dense per row —
//   full coalescing) into an LDS slab, emits two kt fragment-tiles.
// blocks 1024..1791 -> W permute into the contiguous layout.
// (unchanged from round 7)
// ---------------------------------------------------------------------------
__global__ __launch_bounds__(256) void prep(
    const float* __restrict__ x, const float* __restrict__ h,
    const float* __restrict__ Wir, const float* __restrict__ Whr,
    const float* __restrict__ Wiz, const float* __restrict__ Whz,
    const float* __restrict__ Win, const float* __restrict__ Whn,
    _Float16* __restrict__ wperm) {
  __shared__ __align__(16) float xt[128 * 68];  // 34.8 KB (pad 68)
  __shared__ __align__(16) float ht[128 * 68];
  const int b = blockIdx.x;
  const int t = threadIdx.x;

  if (b >= 1024) {
    // ---- W permute (contiguous layout) ----
    const int b2 = b - 1024;
    const int w = b2 >> 7;
    const int rem = b2 & 127;
    const int ki = rem >> 3;
    const int nt = rem & 7;
    const float* W = (w == 0) ? Wir : (w == 1) ? Whr : (w == 2) ? Wiz
                   : (w == 3) ? Whz : (w == 4) ? Win : Whn;
    const int k0 = ki * 32, n0 = nt * 64;
    const int kk = t >> 3;
    const int nn = (t & 7) * 8;
    const float* src = W + (k0 + kk) * 512 + n0 + nn;
    float4 f0 = *(const float4*)(src);
    float4 f1 = *(const float4*)(src + 4);
    float* drow = xt + kk * 68 + nn;
    *(float4*)(drow) = f0;
    *(float4*)(drow + 4) = f1;
    __syncthreads();
    const int u = t >> 6, l = t & 63;
    const int nloc = 16 * u + (l & 15);
    const int kbase = 8 * (l >> 4);
    half8 vh2, vl2;
#pragma unroll
    for (int j = 0; j < 8; ++j) {
      float f = xt[(kbase + j) * 68 + nloc];
      _Float16 hi = (_Float16)f;
      _Float16 lo = (_Float16)(f - (float)hi);
      vh2[j] = hi;
      vl2[j] = lo;
    }
    const size_t base = ((size_t)((nt * 16 + ki) * 12)) * 2048 + t * 8;
    *(half8*)(wperm + base + (size_t)w * 2048) = vh2;
    *(half8*)(wperm + base + (size_t)(6 + w) * 2048) = vl2;
    return;
  }

  // ---- x/h -> aperm (kt-pair slab) ----
  const int mt = b >> 3;        // 0..127
  const int kp = b & 7;         // kt pair: kt = kp*2 + ii
#pragma unroll
  for (int p = 0; p < 2; ++p) {
    const int r = (t >> 2) + p * 64;
    const int c = (t & 3) * 16;
    const float* sx = x + ((size_t)(mt * 128 + r)) * 512 + kp * 64 + c;
    const float* sh = h + ((size_t)(mt * 128 + r)) * 512 + kp * 64 + c;
    float4 a0 = *(const float4*)(sx);
    float4 a1 = *(const float4*)(sx + 4);
    float4 a2 = *(const float4*)(sx + 8);
    float4 a3 = *(const float4*)(sx + 12);
    float4 b0 = *(const float4*)(sh);
    float4 b1 = *(const float4*)(sh + 4);
    float4 b2 = *(const float4*)(sh + 8);
    float4 b3 = *(const float4*)(sh + 12);
    float* dx = xt + r * 68 + c;
    float* dh = ht + r * 68 + c;
    *(float4*)(dx) = a0; *(float4*)(dx + 4) = a1;
    *(float4*)(dx + 8) = a2; *(float4*)(dx + 12) = a3;
    *(float4*)(dh) = b0; *(float4*)(dh + 4) = b1;
    *(float4*)(dh + 8) = b2; *(float4*)(dh + 12) = b3;
  }
  __syncthreads();

#pragma unroll
  for (int ii = 0; ii < 2; ++ii) {
    const int kt = kp * 2 + ii;
    const int cb = ii * 32;  // column base within the 64-col slab
    _Float16* dst = wperm + APERM_OFF + ((size_t)(mt * 16 + kt)) * 16384;
#pragma unroll
    for (int hc = 0; hc < 2; ++hc) {
      const int cc = t + hc * 256;
      const int m = 16 * (cc >> 6) + (cc & 15);
      const int kA = 8 * ((cc >> 4) & 3);
      half8 xh, xl, hh, hl;
#pragma unroll
      for (int j = 0; j < 8; ++j) {
        float fx = xt[m * 68 + cb + kA + j];
        float fh = ht[m * 68 + cb + kA + j];
        _Float16 a = (_Float16)fx;
        xh[j] = a; xl[j] = (_Float16)(fx - (float)a);
        _Float16 bb = (_Float16)fh;
        hh[j] = bb; hl[j] = (_Float16)(fh - (float)bb);
      }
      *(half8*)(dst + 0 * 4096 + cc * 8) = xh;
      *(half8*)(dst + 1 * 4096 + cc * 8) = xl;
      *(half8*)(dst + 2 * 4096 + cc * 8) = hh;
      *(half8*)(dst + 3 * 4096 + cc * 8) = hl;
    }
  }
}

// ---------------------------------------------------------------------------
// gru_fused4: NO LDS, NO barriers.
//   Everything is fragment-ordered + cache-resident: A slice (32 KB/kt,
//   mt pinned to this XCD) is read identically by all 4 waves -> wave 0
//   warms L1 (32 KB = one kt slice), waves 1-3 hit L1. W frags come from
//   L2. With zero barriers there is NO vmcnt(0) drain point anywhere:
//   waves drift freely and the compiler hoists kt+1 loads under kt's
//   144-MFMA cluster. This removes the lockstep stall that capped every
//   barrier variant (R4-R7: 137-149 us, MfmaUtil 47-52).
//   Per k-step per wave: 12 W loads + 32 A loads + 144 MFMA.
// ---------------------------------------------------------------------------
__global__ __launch_bounds__(256, 2) void gru_fused4(
    const float* __restrict__ h, const _Float16* __restrict__ wperm,
    const float* __restrict__ br, const float* __restrict__ bz,
    const float* __restrict__ bn, float* __restrict__ out) {
  const int t = threadIdx.x;
  const int lane = t & 63;
  const int wv = t >> 6;          // wave = 16-col group (wn)
  const int bid = blockIdx.x;
  const int xcd = bid & 7;
  const int g = bid >> 3;
  const int nt = g & 7;
  const int mt = (g >> 3) * 8 + xcd;   // mt%8==xcd -> aperm L2-local
  const int m0 = mt * 128;
  const int n0 = nt * 64;
  // per-lane A base: chunk c = i*64 + lane at c*8 -> i*512 + lane*8
  const _Float16* aperm = wperm + APERM_OFF + (size_t)mt * 16 * 16384
                          + (size_t)lane * 8;

  floatx4 acc_r[8] = {};
  floatx4 acc_z[8] = {};
  floatx4 acc_in[8] = {};
  floatx4 acc_hn[8] = {};

#pragma unroll 2
  for (int kt = 0; kt < 16; ++kt) {
    const _Float16* A = aperm + (size_t)kt * 16384;
    const _Float16* wb = wperm + ((size_t)((nt * 16 + kt) * 12)) * 2048
                         + wv * 512 + lane * 8;

    // --- 12 W fragments (L2-hot, 16B/lane coalesced) ---
    half8 bh0 = *(const half8*)(wb + (size_t)0 * 2048);
    half8 bh1 = *(const half8*)(wb + (size_t)1 * 2048);
    half8 bh2 = *(const half8*)(wb + (size_t)2 * 2048);
    half8 bh3 = *(const half8*)(wb + (size_t)3 * 2048);
    half8 bh4 = *(const half8*)(wb + (size_t)4 * 2048);
    half8 bh5 = *(const half8*)(wb + (size_t)5 * 2048);
    half8 bl0 = *(const half8*)(wb + (size_t)6 * 2048);
    half8 bl1 = *(const half8*)(wb + (size_t)7 * 2048);
    half8 bl2 = *(const half8*)(wb + (size_t)8 * 2048);
    half8 bl3 = *(const half8*)(wb + (size_t)9 * 2048);
    half8 bl4 = *(const half8*)(wb + (size_t)10 * 2048);
    half8 bl5 = *(const half8*)(wb + (size_t)11 * 2048);

    // --- 8 m-subs x {4 A loads (L1-hot) + 18 MFMA} ---
    __builtin_amdgcn_s_setprio(1);
#pragma unroll
    for (int i = 0; i < 8; ++i) {
      const int ao = i * 512;
      half8 axh = *(const half8*)(A + 0 * 4096 + ao);
      half8 axl = *(const half8*)(A + 1 * 4096 + ao);
      half8 ahh = *(const half8*)(A + 2 * 4096 + ao);
      half8 ahl = *(const half8*)(A + 3 * 4096 + ao);
      acc_r[i]  = __builtin_amdgcn_mfma_f32_16x16x32_f16(axh, bh0, acc_r[i], 0, 0, 0);
      acc_z[i]  = __builtin_amdgcn_mfma_f32_16x16x32_f16(axh, bh2, acc_z[i], 0, 0, 0);
      acc_in[i] = __builtin_amdgcn_mfma_f32_16x16x32_f16(axh, bh4, acc_in[i], 0, 0, 0);
      acc_r[i]  = __builtin_amdgcn_mfma_f32_16x16x32_f16(axl, bh0, acc_r[i], 0, 0, 0);
      acc_z[i]  = __builtin_amdgcn_mfma_f32_16x16x32_f16(axl, bh2, acc_z[i], 0, 0, 0);
      acc_in[i] = __builtin_amdgcn_mfma_f32_16x16x32_f16(axl, bh4, acc_in[i], 0, 0, 0);
      acc_r[i]  = __builtin_amdgcn_mfma_f32_16x16x32_f16(ahh, bh1, acc_r[i], 0, 0, 0);
      acc_z[i]  = __builtin_amdgcn_mfma_f32_16x16x32_f16(ahh, bh3, acc_z[i], 0, 0, 0);
      acc_hn[i] = __builtin_amdgcn_mfma_f32_16x16x32_f16(ahh, bh5, acc_hn[i], 0, 0, 0);
      acc_r[i]  = __builtin_amdgcn_mfma_f32_16x16x32_f16(ahl, bh1, acc_r[i], 0, 0, 0);
      acc_z[i]  = __builtin_amdgcn_mfma_f32_16x16x32_f16(ahl, bh3, acc_z[i], 0, 0, 0);
      acc_hn[i] = __builtin_amdgcn_mfma_f32_16x16x32_f16(ahl, bh5, acc_hn[i], 0, 0, 0);
      acc_r[i]  = __builtin_amdgcn_mfma_f32_16x16x32_f16(axh, bl0, acc_r[i], 0, 0, 0);
      acc_z[i]  = __builtin_amdgcn_mfma_f32_16x16x32_f16(axh, bl2, acc_z[i], 0, 0, 0);
      acc_in[i] = __builtin_amdgcn_mfma_f32_16x16x32_f16(axh, bl4, acc_in[i], 0, 0, 0);
      acc_r[i]  = __builtin_amdgcn_mfma_f32_16x16x32_f16(ahh, bl1, acc_r[i], 0, 0, 0);
      acc_z[i]  = __builtin_amdgcn_mfma_f32_16x16x32_f16(ahh, bl3, acc_z[i], 0, 0, 0);
      acc_hn[i] = __builtin_amdgcn_mfma_f32_16x16x32_f16(ahh, bl5, acc_hn[i], 0, 0, 0);
    }
    __builtin_amdgcn_s_setprio(0);
  }

  // --- epilogue: gates + h_new. C/D layout: col = lane&15, row = quad*4+reg
  const int quad = lane >> 4;
  const int col = lane & 15;
  const int n = n0 + wv * 16 + col;
  const float vbr = br[n], vbz = bz[n], vbn = bn[n];
#pragma unroll
  for (int i = 0; i < 8; ++i) {
    const int mbase = m0 + i * 16 + quad * 4;
#pragma unroll
    for (int r = 0; r < 4; ++r) {
      const int m = mbase + r;
      const float gr = acc_r[i][r] + vbr;
      const float gz = acc_z[i][r] + vbz;
      const float rg = 1.0f / (1.0f + __expf(-gr));
      const float zg = 1.0f / (1.0f + __expf(-gz));
      const float gn = acc_in[i][r] + rg * acc_hn[i][r] + vbn;
      const float e2 = __expf(2.0f * gn);          // inf-safe: tanh->+/-1
      const float ntv = 1.0f - 2.0f / (e2 + 1.0f);
      const float hp = h[m * 512 + n];
      out[m * 512 + n] = (1.0f - zg) * ntv + zg * hp;
    }
  }
}

// ---------------------------------------------------------------------------
// Fallback pair (ws too small for aperm): old W layout + R3-style kernel.
// ---------------------------------------------------------------------------
__global__ __launch_bounds__(256) void permute_w_old(
    const float* __restrict__ Wir, const float* __restrict__ Whr,
    const float* __restrict__ Wiz, const float* __restrict__ Whz,
    const float* __restrict__ Win, const float* __restrict__ Whn,
    _Float16* __restrict__ wperm) {
  __shared__ __align__(16) float tile[32 * 68];
  const int b = blockIdx.x;
  const int t = threadIdx.x;
  const int w = b >> 7;
  const int rem = b & 127;
  const int ki = rem >> 3;
  const int nt = rem & 7;
  const float* W = (w == 0) ? Wir : (w == 1) ? Whr : (w == 2) ? Wiz
                 : (w == 3) ? Whz : (w == 4) ? Win : Whn;
  const int k0 = ki * 32, n0 = nt * 64;
  const int kk = t >> 3;
  const int nn = (t & 7) * 8;
  const float* src = W + (k0 + kk) * 512 + n0 + nn;
  float4 f0 = *(const float4*)(src);
  float4 f1 = *(const float4*)(src + 4);
  float* drow = tile + kk * 68 + nn;
  *(float4*)(drow) = f0;
  *(float4*)(drow + 4) = f1;
  __syncthreads();
  const int u = t >> 6, l = t & 63;
  const int nloc = 16 * u + (l & 15);
  const int kbase = 8 * (l >> 4);
  half8 vh2, vl2;
#pragma unroll
  for (int j = 0; j < 8; ++j) {
    float f = tile[(kbase + j) * 68 + nloc];
    _Float16 hi = (_Float16)f;
    _Float16 lo = (_Float16)(f - (float)hi);
    vh2[j] = hi;
    vl2[j] = lo;
  }
  const size_t off = ((size_t)((w * 8 + nt) * 16 + ki)) * 2048 + t * 8;
  *(half8*)(wperm + off) = vh2;
  *(half8*)(wperm + WLO_OFF + off) = vl2;
}

__global__ __launch_bounds__(256, 2) void gru_fused_fb(
    const float* __restrict__ x, const float* __restrict__ h,
    const _Float16* __restrict__ wperm,
    const float* __restrict__ br, const float* __restrict__ bz,
    const float* __restrict__ bn, float* __restrict__ out) {
  __shared__ __align__(16) _Float16 ldsA[2 * 4 * 4096];
  const int t = threadIdx.x;
  const int lane = t & 63;
  const int wn = t >> 6;
  const int bid = blockIdx.x;
  const int nt = bid & 7;
  const int mt = bid >> 3;
  const int m0 = mt * 128;
  const int n0 = nt * 64;
  const _Float16* wlo = wperm + WLO_OFF;

  floatx4 acc_r[8] = {};
  floatx4 acc_z[8] = {};
  floatx4 acc_in[8] = {};
  floatx4 acc_hn[8] = {};

  const int mA = 16 * (t >> 6) + (t & 15);
  const int kA = 8 * ((t >> 4) & 3);
  const float* px0 = x + (m0 + mA) * 512 + kA;
  const float* ph0 = h + (m0 + mA) * 512 + kA;
  const float* px1 = px0 + 64 * 512;
  const float* ph1 = ph0 + 64 * 512;
  const int c0 = t, c1 = t + 256;

  {
    float v[4][8];
    *(float4*)&v[0][0] = *(const float4*)(px0); *(float4*)&v[0][4] = *(const float4*)(px0 + 4);
    *(float4*)&v[1][0] = *(const float4*)(px1); *(float4*)&v[1][4] = *(const float4*)(px1 + 4);
    *(float4*)&v[2][0] = *(const float4*)(ph0); *(float4*)&v[2][4] = *(const float4*)(ph0 + 4);
    *(float4*)&v[3][0] = *(const float4*)(ph1); *(float4*)&v[3][4] = *(const float4*)(ph1 + 4);
#pragma unroll
    for (int g = 0; g < 4; ++g) {
      half8 hi, lo;
#pragma unroll
      for (int j = 0; j < 8; ++j) {
        _Float16 a = (_Float16)v[g][j];
        hi[j] = a;
        lo[j] = (_Float16)(v[g][j] - (float)a);
      }
      const int c = (g & 1) ? c1 : c0;
      const int part = (g >> 1) * 2;
      *(half8*)(ldsA + (part + 0) * 4096 + c * 8) = hi;
      *(half8*)(ldsA + (part + 1) * 4096 + c * 8) = lo;
    }
  }
  __syncthreads();

#pragma unroll 2
  for (int kt = 0; kt < 16; ++kt) {
    const _Float16* A = ldsA + (kt & 1) * 16384;
    const size_t tb = ((size_t)(nt * 16 + kt)) * 2048 + wn * 512 + lane * 8;
    half8 bh_ir = *(const half8*)(wperm + tb + 0 * WMAT_STRIDE);
    half8 bh_hr = *(const half8*)(wperm + tb + 1 * WMAT_STRIDE);
    half8 bh_iz = *(const half8*)(wperm + tb + 2 * WMAT_STRIDE);
    half8 bh_hz = *(const half8*)(wperm + tb + 3 * WMAT_STRIDE);
    half8 bh_in = *(const half8*)(wperm + tb + 4 * WMAT_STRIDE);
    half8 bh_hn = *(const half8*)(wperm + tb + 5 * WMAT_STRIDE);
    half8 bl_ir = *(const half8*)(wlo + tb + 0 * WMAT_STRIDE);
    half8 bl_hr = *(const half8*)(wlo + tb + 1 * WMAT_STRIDE);
    half8 bl_iz = *(const half8*)(wlo + tb + 2 * WMAT_STRIDE);
    half8 bl_hz = *(const half8*)(wlo + tb + 3 * WMAT_STRIDE);
    half8 bl_in = *(const half8*)(wlo + tb + 4 * WMAT_STRIDE);
    half8 bl_hn = *(const half8*)(wlo + tb + 5 * WMAT_STRIDE);
    __builtin_amdgcn_sched_barrier(0);

    float v[4][8];
    if (kt < 15) {
      const int k0 = (kt + 1) * 32;
      *(float4*)&v[0][0] = *(const float4*)(px0 + k0); *(float4*)&v[0][4] = *(const float4*)(px0 + k0 + 4);
      *(float4*)&v[1][0] = *(const float4*)(px1 + k0); *(float4*)&v[1][4] = *(const float4*)(px1 + k0 + 4);
      *(float4*)&v[2][0] = *(const float4*)(ph0 + k0); *(float4*)&v[2][4] = *(const float4*)(ph0 + k0 + 4);
      *(float4*)&v[3][0] = *(const float4*)(ph1 + k0); *(float4*)&v[3][4] = *(const float4*)(ph1 + k0 + 4);
    }
    __builtin_amdgcn_sched_barrier(0);

    __builtin_amdgcn_s_setprio(1);
#pragma unroll
    for (int i = 0; i < 8; ++i) {
      const int ao = (i * 64 + lane) * 8;
      half8 axh = *(const half8*)(A + 0 * 4096 + ao);
      half8 axl = *(const half8*)(A + 1 * 4096 + ao);
      half8 ahh = *(const half8*)(A + 2 * 4096 + ao);
      half8 ahl = *(const half8*)(A + 3 * 4096 + ao);
      acc_r[i]  = __builtin_amdgcn_mfma_f32_16x16x32_f16(axh, bh_ir, acc_r[i], 0, 0, 0);
      acc_r[i]  = __builtin_amdgcn_mfma_f32_16x16x32_f16(ahh, bh_hr, acc_r[i], 0, 0, 0);
      acc_z[i]  = __builtin_amdgcn_mfma_f32_16x16x32_f16(axh, bh_iz, acc_z[i], 0, 0, 0);
      acc_z[i]  = __builtin_amdgcn_mfma_f32_16x16x32_f16(ahh, bh_hz, acc_z[i], 0, 0, 0);
      acc_in[i] = __builtin_amdgcn_mfma_f32_16x16x32_f16(axh, bh_in, acc_in[i], 0, 0, 0);
      acc_hn[i] = __builtin_amdgcn_mfma_f32_16x16x32_f16(ahh, bh_hn, acc_hn[i], 0, 0, 0);
      acc_r[i]  = __builtin_amdgcn_mfma_f32_16x16x32_f16(axl, bh_ir, acc_r[i], 0, 0, 0);
      acc_r[i]  = __builtin_amdgcn_mfma_f32_16x16x32_f16(ahl, bh_hr, acc_r[i], 0, 0, 0);
      acc_z[i]  = __builtin_amdgcn_mfma_f32_16x16x32_f16(axl, bh_iz, acc_z[i], 0, 0, 0);
      acc_z[i]  = __builtin_amdgcn_mfma_f32_16x16x32_f16(ahl, bh_hz, acc_z[i], 0, 0, 0);
      acc_in[i] = __builtin_amdgcn_mfma_f32_16x16x32_f16(axl, bh_in, acc_in[i], 0, 0, 0);
      acc_hn[i] = __builtin_amdgcn_mfma_f32_16x16x32_f16(ahl, bh_hn, acc_hn[i], 0, 0, 0);
      acc_r[i]  = __builtin_amdgcn_mfma_f32_16x16x32_f16(axh, bl_ir, acc_r[i], 0, 0, 0);
      acc_r[i]  = __builtin_amdgcn_mfma_f32_16x16x32_f16(ahh, bl_hr, acc_r[i], 0, 0, 0);
      acc_z[i]  = __builtin_amdgcn_mfma_f32_16x16x32_f16(axh, bl_iz, acc_z[i], 0, 0, 0);
      acc_z[i]  = __builtin_amdgcn_mfma_f32_16x16x32_f16(ahh, bl_hz, acc_z[i], 0, 0, 0);
      acc_in[i] = __builtin_amdgcn_mfma_f32_16x16x32_f16(axh, bl_in, acc_in[i], 0, 0, 0);
      acc_hn[i] = __builtin_amdgcn_mfma_f32_16x16x32_f16(ahh, bl_hn, acc_hn[i], 0, 0, 0);
    }
    __builtin_amdgcn_s_setprio(0);

    if (kt < 15) {
      _Float16* base = ldsA + ((kt & 1) ^ 1) * 16384;
#pragma unroll
      for (int g = 0; g < 4; ++g) {
        half8 hi, lo;
#pragma unroll
        for (int j = 0; j < 8; ++j) {
          _Float16 a = (_Float16)v[g][j];
          hi[j] = a;
          lo[j] = (_Float16)(v[g][j] - (float)a);
        }
        const int c = (g & 1) ? c1 : c0;
        const int part = (g >> 1) * 2;
        *(half8*)(base + (part + 0) * 4096 + c * 8) = hi;
        *(half8*)(base + (part + 1) * 4096 + c * 8) = lo;
      }
    }
    __syncthreads();
  }

  const int quad = lane >> 4;
  const int col = lane & 15;
  const int n = n0 + wn * 16 + col;
  const float vbr = br[n], vbz = bz[n], vbn = bn[n];
#pragma unroll
  for (int i = 0; i < 8; ++i) {
    const int mbase = m0 + i * 16 + quad * 4;
#pragma unroll
    for (int r = 0; r < 4; ++r) {
      const int m = mbase + r;
      const float gr = acc_r[i][r] + vbr;
      const float gz = acc_z[i][r] + vbz;
      const float rg = 1.0f / (1.0f + __expf(-gr));
      const float zg = 1.0f / (1.0f + __expf(-gz));
      const float gn = acc_in[i][r] + rg * acc_hn[i][r] + vbn;
      const float e2 = __expf(2.0f * gn);
      const float ntv = 1.0f - 2.0f / (e2 + 1.0f);
      const float hp = h[m * 512 + n];
      out[m * 512 + n] = (1.0f - zg) * ntv + zg * hp;
    }
  }
}

extern "C" void kernel_launch(void* const* d_in, const int* in_sizes, int n_in,
                              void* d_out, int out_size, void* d_ws, size_t ws_size,
                              hipStream_t stream) {
  const float* x   = (const float*)d_in[0];
  const float* h   = (const float*)d_in[1];
  const float* Wir = (const float*)d_in[2];
  const float* Whr = (const float*)d_in[3];
  const float* br  = (const float*)d_in[4];
  const float* Wiz = (const float*)d_in[5];
  const float* Whz = (const float*)d_in[6];
  const float* bz  = (const float*)d_in[7];
  const float* Win = (const float*)d_in[8];
  const float* Whn = (const float*)d_in[9];
  const float* bn  = (const float*)d_in[10];
  float* out = (float*)d_out;
  _Float16* wperm = (_Float16*)d_ws;

  const size_t need_bytes = (APERM_OFF + APERM_HALFS) * 2;  // ~73.4 MB
  if (ws_size >= need_bytes) {
    prep<<<1792, 256, 0, stream>>>(x, h, Wir, Whr, Wiz, Whz, Win, Whn, wperm);
    gru_fused4<<<1024, 256, 0, stream>>>(h, wperm, br, bz, bn, out);
  } else {
    permute_w_old<<<768, 256, 0, stream>>>(Wir, Whr, Wiz, Whz, Win, Whn, wperm);
    gru_fused_fb<<<1024, 256, 0, stream>>>(x, h, wperm, br, bz, bn, out);
  }
}

// Round 9
// 258.484 us; speedup vs baseline: 1.1537x; 1.1537x over previous
//
#include <hip/hip_runtime.h>
#include <hip/hip_fp16.h>

typedef _Float16 half8 __attribute__((ext_vector_type(8)));
typedef float floatx4 __attribute__((ext_vector_type(4)));

#define AS1 __attribute__((address_space(1)))
#define AS3 __attribute__((address_space(3)))

// workspace layout (halfs):
//   [0, WLO_OFF)            W hi fragments, strided layout:
//       ((w*8+nt)*16+kt)*2048 + wv*512 + lane*8   (w = matrix 0..5)
//   [WLO_OFF, 2*WLO_OFF)    W lo fragments (same indexing)
//   [APERM_OFF, ...)        x/h hi/lo fragment-ordered (per mt,kt:
//       Xh|Xl|Hh|Hl x 4096 halfs)
// NOTE: R7's contiguous W layout measured SLOWER (148.5 vs 137 us) than this
// strided one (L2 hotspotting on the shared 24KB chunk) — keep strided.
#define WLO_OFF (6 * 512 * 512)
#define WMAT_STRIDE ((size_t)(8 * 16 * 2048))
#define APERM_OFF ((size_t)(2 * WLO_OFF))
#define APERM_HALFS ((size_t)128 * 16 * 4 * 4096)

__device__ __forceinline__ void async_lds16(const void* g, void* l) {
  __builtin_amdgcn_global_load_lds((const AS1 void*)g, (AS3 void*)l, 16, 0, 0);
}

// ---------------------------------------------------------------------------
// prep: blocks 0..1023 -> x/h fp32 to fragment-ordered f16 hi/lo (aperm).
//   Block = (mt, kt-pair): reads 128 rows x 64 cols (256B dense per row —
//   full coalescing) into an LDS slab, emits two kt fragment-tiles.
// blocks 1024..1791 -> W permute into the STRIDED (R4-verified) layout.
// ---------------------------------------------------------------------------
__global__ __launch_bounds__(256) void prep(
    const float* __restrict__ x, const float* __restrict__ h,
    const float* __restrict__ Wir, const float* __restrict__ Whr,
    const float* __restrict__ Wiz, const float* __restrict__ Whz,
    const float* __restrict__ Win, const float* __restrict__ Whn,
    _Float16* __restrict__ wperm) {
  __shared__ __align__(16) float xt[128 * 68];  // 34.8 KB (pad 68)
  __shared__ __align__(16) float ht[128 * 68];
  const int b = blockIdx.x;
  const int t = threadIdx.x;

  if (b >= 1024) {
    // ---- W permute (strided layout) ----
    const int b2 = b - 1024;
    const int w = b2 >> 7;
    const int rem = b2 & 127;
    const int ki = rem >> 3;
    const int nt = rem & 7;
    const float* W = (w == 0) ? Wir : (w == 1) ? Whr : (w == 2) ? Wiz
                   : (w == 3) ? Whz : (w == 4) ? Win : Whn;
    const int k0 = ki * 32, n0 = nt * 64;
    const int kk = t >> 3;
    const int nn = (t & 7) * 8;
    const float* src = W + (k0 + kk) * 512 + n0 + nn;
    float4 f0 = *(const float4*)(src);
    float4 f1 = *(const float4*)(src + 4);
    float* drow = xt + kk * 68 + nn;
    *(float4*)(drow) = f0;
    *(float4*)(drow + 4) = f1;
    __syncthreads();
    const int u = t >> 6, l = t & 63;
    const int nloc = 16 * u + (l & 15);
    const int kbase = 8 * (l >> 4);
    half8 vh2, vl2;
#pragma unroll
    for (int j = 0; j < 8; ++j) {
      float f = xt[(kbase + j) * 68 + nloc];
      _Float16 hi = (_Float16)f;
      _Float16 lo = (_Float16)(f - (float)hi);
      vh2[j] = hi;
      vl2[j] = lo;
    }
    const size_t off = ((size_t)((w * 8 + nt) * 16 + ki)) * 2048 + t * 8;
    *(half8*)(wperm + off) = vh2;
    *(half8*)(wperm + WLO_OFF + off) = vl2;
    return;
  }

  // ---- x/h -> aperm (kt-pair slab, fully coalesced reads) ----
  const int mt = b >> 3;        // 0..127
  const int kp = b & 7;         // kt pair: kt = kp*2 + ii
#pragma unroll
  for (int p = 0; p < 2; ++p) {
    const int r = (t >> 2) + p * 64;
    const int c = (t & 3) * 16;
    const float* sx = x + ((size_t)(mt * 128 + r)) * 512 + kp * 64 + c;
    const float* sh = h + ((size_t)(mt * 128 + r)) * 512 + kp * 64 + c;
    float4 a0 = *(const float4*)(sx);
    float4 a1 = *(const float4*)(sx + 4);
    float4 a2 = *(const float4*)(sx + 8);
    float4 a3 = *(const float4*)(sx + 12);
    float4 b0 = *(const float4*)(sh);
    float4 b1 = *(const float4*)(sh + 4);
    float4 b2 = *(const float4*)(sh + 8);
    float4 b3 = *(const float4*)(sh + 12);
    float* dx = xt + r * 68 + c;
    float* dh = ht + r * 68 + c;
    *(float4*)(dx) = a0; *(float4*)(dx + 4) = a1;
    *(float4*)(dx + 8) = a2; *(float4*)(dx + 12) = a3;
    *(float4*)(dh) = b0; *(float4*)(dh + 4) = b1;
    *(float4*)(dh + 8) = b2; *(float4*)(dh + 12) = b3;
  }
  __syncthreads();

#pragma unroll
  for (int ii = 0; ii < 2; ++ii) {
    const int kt = kp * 2 + ii;
    const int cb = ii * 32;  // column base within the 64-col slab
    _Float16* dst = wperm + APERM_OFF + ((size_t)(mt * 16 + kt)) * 16384;
#pragma unroll
    for (int hc = 0; hc < 2; ++hc) {
      const int cc = t + hc * 256;
      const int m = 16 * (cc >> 6) + (cc & 15);
      const int kA = 8 * ((cc >> 4) & 3);
      half8 xh, xl, hh, hl;
#pragma unroll
      for (int j = 0; j < 8; ++j) {
        float fx = xt[m * 68 + cb + kA + j];
        float fh = ht[m * 68 + cb + kA + j];
        _Float16 a = (_Float16)fx;
        xh[j] = a; xl[j] = (_Float16)(fx - (float)a);
        _Float16 bb = (_Float16)fh;
        hh[j] = bb; hl[j] = (_Float16)(fh - (float)bb);
      }
      *(half8*)(dst + 0 * 4096 + cc * 8) = xh;
      *(half8*)(dst + 1 * 4096 + cc * 8) = xl;
      *(half8*)(dst + 2 * 4096 + cc * 8) = hh;
      *(half8*)(dst + 3 * 4096 + cc * 8) = hl;
    }
  }
}

// ---------------------------------------------------------------------------
// gru_fused2: EXACT round-4 kernel (session best: 137 us, MfmaUtil 52%).
//   - 256 threads, 4 waves x (128m x 16n); strided W layout; prologue DMA;
//     W 12-load burst -> DMA kt+1 -> 144 MFMA -> one __syncthreads; unroll 2.
//   - Bracketing evidence: deeper prefetch spills (R5), 8 waves doubles W
//     traffic (R6), contiguous W hotspots L2 (R7), no-LDS spills (R8).
// ---------------------------------------------------------------------------
__global__ __launch_bounds__(256, 2) void gru_fused2(
    const float* __restrict__ h, const _Float16* __restrict__ wperm,
    const float* __restrict__ br, const float* __restrict__ bz,
    const float* __restrict__ bn, float* __restrict__ out) {
  __shared__ __align__(16) _Float16 ldsA[2 * 4 * 4096];  // 64 KB dbuf

  const int t = threadIdx.x;
  const int lane = t & 63;
  const int wv = t >> 6;
  const int bid = blockIdx.x;
  const int xcd = bid & 7;
  const int g = bid >> 3;
  const int nt = g & 7;
  const int mt = (g >> 3) * 8 + xcd;   // mt%8==xcd -> aperm L2-local
  const int m0 = mt * 128;
  const int n0 = nt * 64;
  const _Float16* wlo = wperm + WLO_OFF;
  const _Float16* aperm = wperm + APERM_OFF + (size_t)mt * 16 * 16384;

  floatx4 acc_r[8] = {};
  floatx4 acc_z[8] = {};
  floatx4 acc_in[8] = {};
  floatx4 acc_hn[8] = {};

  {
    const _Float16* asrc = aperm + wv * 4096 + lane * 8;
    _Float16* adst = ldsA + wv * 4096;
#pragma unroll
    for (int q = 0; q < 8; ++q) async_lds16(asrc + q * 512, adst + q * 512);
  }
  __syncthreads();

#pragma unroll 2
  for (int kt = 0; kt < 16; ++kt) {
    const _Float16* A = ldsA + (kt & 1) * 16384;

    const size_t tb = ((size_t)(nt * 16 + kt)) * 2048 + wv * 512 + lane * 8;
    half8 bh_ir = *(const half8*)(wperm + tb + 0 * WMAT_STRIDE);
    half8 bh_hr = *(const half8*)(wperm + tb + 1 * WMAT_STRIDE);
    half8 bh_iz = *(const half8*)(wperm + tb + 2 * WMAT_STRIDE);
    half8 bh_hz = *(const half8*)(wperm + tb + 3 * WMAT_STRIDE);
    half8 bh_in = *(const half8*)(wperm + tb + 4 * WMAT_STRIDE);
    half8 bh_hn = *(const half8*)(wperm + tb + 5 * WMAT_STRIDE);
    half8 bl_ir = *(const half8*)(wlo + tb + 0 * WMAT_STRIDE);
    half8 bl_hr = *(const half8*)(wlo + tb + 1 * WMAT_STRIDE);
    half8 bl_iz = *(const half8*)(wlo + tb + 2 * WMAT_STRIDE);
    half8 bl_hz = *(const half8*)(wlo + tb + 3 * WMAT_STRIDE);
    half8 bl_in = *(const half8*)(wlo + tb + 4 * WMAT_STRIDE);
    half8 bl_hn = *(const half8*)(wlo + tb + 5 * WMAT_STRIDE);
    __builtin_amdgcn_sched_barrier(0);

    if (kt < 15) {
      const _Float16* asrc =
          aperm + (size_t)(kt + 1) * 16384 + wv * 4096 + lane * 8;
      _Float16* adst = ldsA + ((kt & 1) ^ 1) * 16384 + wv * 4096;
#pragma unroll
      for (int q = 0; q < 8; ++q) async_lds16(asrc + q * 512, adst + q * 512);
    }
    __builtin_amdgcn_sched_barrier(0);

    __builtin_amdgcn_s_setprio(1);
#pragma unroll
    for (int i = 0; i < 8; ++i) {
      const int ao = (i * 64 + lane) * 8;
      half8 axh = *(const half8*)(A + 0 * 4096 + ao);
      half8 axl = *(const half8*)(A + 1 * 4096 + ao);
      half8 ahh = *(const half8*)(A + 2 * 4096 + ao);
      half8 ahl = *(const half8*)(A + 3 * 4096 + ao);
      acc_r[i]  = __builtin_amdgcn_mfma_f32_16x16x32_f16(axh, bh_ir, acc_r[i], 0, 0, 0);
      acc_r[i]  = __builtin_amdgcn_mfma_f32_16x16x32_f16(ahh, bh_hr, acc_r[i], 0, 0, 0);
      acc_z[i]  = __builtin_amdgcn_mfma_f32_16x16x32_f16(axh, bh_iz, acc_z[i], 0, 0, 0);
      acc_z[i]  = __builtin_amdgcn_mfma_f32_16x16x32_f16(ahh, bh_hz, acc_z[i], 0, 0, 0);
      acc_in[i] = __builtin_amdgcn_mfma_f32_16x16x32_f16(axh, bh_in, acc_in[i], 0, 0, 0);
      acc_hn[i] = __builtin_amdgcn_mfma_f32_16x16x32_f16(ahh, bh_hn, acc_hn[i], 0, 0, 0);
      acc_r[i]  = __builtin_amdgcn_mfma_f32_16x16x32_f16(axl, bh_ir, acc_r[i], 0, 0, 0);
      acc_r[i]  = __builtin_amdgcn_mfma_f32_16x16x32_f16(ahl, bh_hr, acc_r[i], 0, 0, 0);
      acc_z[i]  = __builtin_amdgcn_mfma_f32_16x16x32_f16(axl, bh_iz, acc_z[i], 0, 0, 0);
      acc_z[i]  = __builtin_amdgcn_mfma_f32_16x16x32_f16(ahl, bh_hz, acc_z[i], 0, 0, 0);
      acc_in[i] = __builtin_amdgcn_mfma_f32_16x16x32_f16(axl, bh_in, acc_in[i], 0, 0, 0);
      acc_hn[i] = __builtin_amdgcn_mfma_f32_16x16x32_f16(ahl, bh_hn, acc_hn[i], 0, 0, 0);
      acc_r[i]  = __builtin_amdgcn_mfma_f32_16x16x32_f16(axh, bl_ir, acc_r[i], 0, 0, 0);
      acc_r[i]  = __builtin_amdgcn_mfma_f32_16x16x32_f16(ahh, bl_hr, acc_r[i], 0, 0, 0);
      acc_z[i]  = __builtin_amdgcn_mfma_f32_16x16x32_f16(axh, bl_iz, acc_z[i], 0, 0, 0);
      acc_z[i]  = __builtin_amdgcn_mfma_f32_16x16x32_f16(ahh, bl_hz, acc_z[i], 0, 0, 0);
      acc_in[i] = __builtin_amdgcn_mfma_f32_16x16x32_f16(axh, bl_in, acc_in[i], 0, 0, 0);
      acc_hn[i] = __builtin_amdgcn_mfma_f32_16x16x32_f16(ahh, bl_hn, acc_hn[i], 0, 0, 0);
    }
    __builtin_amdgcn_s_setprio(0);

    __syncthreads();  // buf[cur] consumed; buf[cur^1] DMA drained + visible
  }

  // --- epilogue: gates + h_new. C/D layout: col = lane&15, row = quad*4+reg
  const int quad = lane >> 4;
  const int col = lane & 15;
  const int n = n0 + wv * 16 + col;
  const float vbr = br[n], vbz = bz[n], vbn = bn[n];
#pragma unroll
  for (int i = 0; i < 8; ++i) {
    const int mbase = m0 + i * 16 + quad * 4;
#pragma unroll
    for (int r = 0; r < 4; ++r) {
      const int m = mbase + r;
      const float gr = acc_r[i][r] + vbr;
      const float gz = acc_z[i][r] + vbz;
      const float rg = 1.0f / (1.0f + __expf(-gr));
      const float zg = 1.0f / (1.0f + __expf(-gz));
      const float gn = acc_in[i][r] + rg * acc_hn[i][r] + vbn;
      const float e2 = __expf(2.0f * gn);          // inf-safe: tanh->+/-1
      const float ntv = 1.0f - 2.0f / (e2 + 1.0f);
      const float hp = h[m * 512 + n];
      out[m * 512 + n] = (1.0f - zg) * ntv + zg * hp;
    }
  }
}

// ---------------------------------------------------------------------------
// Fallback pair (ws too small for aperm): W permute + R3-style kernel that
// splits x/h in-kernel (no aperm needed).
// ---------------------------------------------------------------------------
__global__ __launch_bounds__(256) void permute_w_old(
    const float* __restrict__ Wir, const float* __restrict__ Whr,
    const float* __restrict__ Wiz, const float* __restrict__ Whz,
    const float* __restrict__ Win, const float* __restrict__ Whn,
    _Float16* __restrict__ wperm) {
  __shared__ __align__(16) float tile[32 * 68];
  const int b = blockIdx.x;
  const int t = threadIdx.x;
  const int w = b >> 7;
  const int rem = b & 127;
  const int ki = rem >> 3;
  const int nt = rem & 7;
  const float* W = (w == 0) ? Wir : (w == 1) ? Whr : (w == 2) ? Wiz
                 : (w == 3) ? Whz : (w == 4) ? Win : Whn;
  const int k0 = ki * 32, n0 = nt * 64;
  const int kk = t >> 3;
  const int nn = (t & 7) * 8;
  const float* src = W + (k0 + kk) * 512 + n0 + nn;
  float4 f0 = *(const float4*)(src);
  float4 f1 = *(const float4*)(src + 4);
  float* drow = tile + kk * 68 + nn;
  *(float4*)(drow) = f0;
  *(float4*)(drow + 4) = f1;
  __syncthreads();
  const int u = t >> 6, l = t & 63;
  const int nloc = 16 * u + (l & 15);
  const int kbase = 8 * (l >> 4);
  half8 vh2, vl2;
#pragma unroll
  for (int j = 0; j < 8; ++j) {
    float f = tile[(kbase + j) * 68 + nloc];
    _Float16 hi = (_Float16)f;
    _Float16 lo = (_Float16)(f - (float)hi);
    vh2[j] = hi;
    vl2[j] = lo;
  }
  const size_t off = ((size_t)((w * 8 + nt) * 16 + ki)) * 2048 + t * 8;
  *(half8*)(wperm + off) = vh2;
  *(half8*)(wperm + WLO_OFF + off) = vl2;
}

__global__ __launch_bounds__(256, 2) void gru_fused_fb(
    const float* __restrict__ x, const float* __restrict__ h,
    const _Float16* __restrict__ wperm,
    const float* __restrict__ br, const float* __restrict__ bz,
    const float* __restrict__ bn, float* __restrict__ out) {
  __shared__ __align__(16) _Float16 ldsA[2 * 4 * 4096];
  const int t = threadIdx.x;
  const int lane = t & 63;
  const int wn = t >> 6;
  const int bid = blockIdx.x;
  const int nt = bid & 7;
  const int mt = bid >> 3;
  const int m0 = mt * 128;
  const int n0 = nt * 64;
  const _Float16* wlo = wperm + WLO_OFF;

  floatx4 acc_r[8] = {};
  floatx4 acc_z[8] = {};
  floatx4 acc_in[8] = {};
  floatx4 acc_hn[8] = {};

  const int mA = 16 * (t >> 6) + (t & 15);
  const int kA = 8 * ((t >> 4) & 3);
  const float* px0 = x + (m0 + mA) * 512 + kA;
  const float* ph0 = h + (m0 + mA) * 512 + kA;
  const float* px1 = px0 + 64 * 512;
  const float* ph1 = ph0 + 64 * 512;
  const int c0 = t, c1 = t + 256;

  {
    float v[4][8];
    *(float4*)&v[0][0] = *(const float4*)(px0); *(float4*)&v[0][4] = *(const float4*)(px0 + 4);
    *(float4*)&v[1][0] = *(const float4*)(px1); *(float4*)&v[1][4] = *(const float4*)(px1 + 4);
    *(float4*)&v[2][0] = *(const float4*)(ph0); *(float4*)&v[2][4] = *(const float4*)(ph0 + 4);
    *(float4*)&v[3][0] = *(const float4*)(ph1); *(float4*)&v[3][4] = *(const float4*)(ph1 + 4);
#pragma unroll
    for (int g = 0; g < 4; ++g) {
      half8 hi, lo;
#pragma unroll
      for (int j = 0; j < 8; ++j) {
        _Float16 a = (_Float16)v[g][j];
        hi[j] = a;
        lo[j] = (_Float16)(v[g][j] - (float)a);
      }
      const int c = (g & 1) ? c1 : c0;
      const int part = (g >> 1) * 2;
      *(half8*)(ldsA + (part + 0) * 4096 + c * 8) = hi;
      *(half8*)(ldsA + (part + 1) * 4096 + c * 8) = lo;
    }
  }
  __syncthreads();

#pragma unroll 2
  for (int kt = 0; kt < 16; ++kt) {
    const _Float16* A = ldsA + (kt & 1) * 16384;
    const size_t tb = ((size_t)(nt * 16 + kt)) * 2048 + wn * 512 + lane * 8;
    half8 bh_ir = *(const half8*)(wperm + tb + 0 * WMAT_STRIDE);
    half8 bh_hr = *(const half8*)(wperm + tb + 1 * WMAT_STRIDE);
    half8 bh_iz = *(const half8*)(wperm + tb + 2 * WMAT_STRIDE);
    half8 bh_hz = *(const half8*)(wperm + tb + 3 * WMAT_STRIDE);
    half8 bh_in = *(const half8*)(wperm + tb + 4 * WMAT_STRIDE);
    half8 bh_hn = *(const half8*)(wperm + tb + 5 * WMAT_STRIDE);
    half8 bl_ir = *(const half8*)(wlo + tb + 0 * WMAT_STRIDE);
    half8 bl_hr = *(const half8*)(wlo + tb + 1 * WMAT_STRIDE);
    half8 bl_iz = *(const half8*)(wlo + tb + 2 * WMAT_STRIDE);
    half8 bl_hz = *(const half8*)(wlo + tb + 3 * WMAT_STRIDE);
    half8 bl_in = *(const half8*)(wlo + tb + 4 * WMAT_STRIDE);
    half8 bl_hn = *(const half8*)(wlo + tb + 5 * WMAT_STRIDE);
    __builtin_amdgcn_sched_barrier(0);

    float v[4][8];
    if (kt < 15) {
      const int k0 = (kt + 1) * 32;
      *(float4*)&v[0][0] = *(const float4*)(px0 + k0); *(float4*)&v[0][4] = *(const float4*)(px0 + k0 + 4);
      *(float4*)&v[1][0] = *(const float4*)(px1 + k0); *(float4*)&v[1][4] = *(const float4*)(px1 + k0 + 4);
      *(float4*)&v[2][0] = *(const float4*)(ph0 + k0); *(float4*)&v[2][4] = *(const float4*)(ph0 + k0 + 4);
      *(float4*)&v[3][0] = *(const float4*)(ph1 + k0); *(float4*)&v[3][4] = *(const float4*)(ph1 + k0 + 4);
    }
    __builtin_amdgcn_sched_barrier(0);

    __builtin_amdgcn_s_setprio(1);
#pragma unroll
    for (int i = 0; i < 8; ++i) {
      const int ao = (i * 64 + lane) * 8;
      half8 axh = *(const half8*)(A + 0 * 4096 + ao);
      half8 axl = *(const half8*)(A + 1 * 4096 + ao);
      half8 ahh = *(const half8*)(A + 2 * 4096 + ao);
      half8 ahl = *(const half8*)(A + 3 * 4096 + ao);
      acc_r[i]  = __builtin_amdgcn_mfma_f32_16x16x32_f16(axh, bh_ir, acc_r[i], 0, 0, 0);
      acc_r[i]  = __builtin_amdgcn_mfma_f32_16x16x32_f16(ahh, bh_hr, acc_r[i], 0, 0, 0);
      acc_z[i]  = __builtin_amdgcn_mfma_f32_16x16x32_f16(axh, bh_iz, acc_z[i], 0, 0, 0);
      acc_z[i]  = __builtin_amdgcn_mfma_f32_16x16x32_f16(ahh, bh_hz, acc_z[i], 0, 0, 0);
      acc_in[i] = __builtin_amdgcn_mfma_f32_16x16x32_f16(axh, bh_in, acc_in[i], 0, 0, 0);
      acc_hn[i] = __builtin_amdgcn_mfma_f32_16x16x32_f16(ahh, bh_hn, acc_hn[i], 0, 0, 0);
      acc_r[i]  = __builtin_amdgcn_mfma_f32_16x16x32_f16(axl, bh_ir, acc_r[i], 0, 0, 0);
      acc_r[i]  = __builtin_amdgcn_mfma_f32_16x16x32_f16(ahl, bh_hr, acc_r[i], 0, 0, 0);
      acc_z[i]  = __builtin_amdgcn_mfma_f32_16x16x32_f16(axl, bh_iz, acc_z[i], 0, 0, 0);
      acc_z[i]  = __builtin_amdgcn_mfma_f32_16x16x32_f16(ahl, bh_hz, acc_z[i], 0, 0, 0);
      acc_in[i] = __builtin_amdgcn_mfma_f32_16x16x32_f16(axl, bh_in, acc_in[i], 0, 0, 0);
      acc_hn[i] = __builtin_amdgcn_mfma_f32_16x16x32_f16(ahl, bh_hn, acc_hn[i], 0, 0, 0);
      acc_r[i]  = __builtin_amdgcn_mfma_f32_16x16x32_f16(axh, bl_ir, acc_r[i], 0, 0, 0);
      acc_r[i]  = __builtin_amdgcn_mfma_f32_16x16x32_f16(ahh, bl_hr, acc_r[i], 0, 0, 0);
      acc_z[i]  = __builtin_amdgcn_mfma_f32_16x16x32_f16(axh, bl_iz, acc_z[i], 0, 0, 0);
      acc_z[i]  = __builtin_amdgcn_mfma_f32_16x16x32_f16(ahh, bl_hz, acc_z[i], 0, 0, 0);
      acc_in[i] = __builtin_amdgcn_mfma_f32_16x16x32_f16(axh, bl_in, acc_in[i], 0, 0, 0);
      acc_hn[i] = __builtin_amdgcn_mfma_f32_16x16x32_f16(ahh, bl_hn, acc_hn[i], 0, 0, 0);
    }
    __builtin_amdgcn_s_setprio(0);

    if (kt < 15) {
      _Float16* base = ldsA + ((kt & 1) ^ 1) * 16384;
#pragma unroll
      for (int g = 0; g < 4; ++g) {
        half8 hi, lo;
#pragma unroll
        for (int j = 0; j < 8; ++j) {
          _Float16 a = (_Float16)v[g][j];
          hi[j] = a;
          lo[j] = (_Float16)(v[g][j] - (float)a);
        }
        const int c = (g & 1) ? c1 : c0;
        const int part = (g >> 1) * 2;
        *(half8*)(base + (part + 0) * 4096 + c * 8) = hi;
        *(half8*)(base + (part + 1) * 4096 + c * 8) = lo;
      }
    }
    __syncthreads();
  }

  const int quad = lane >> 4;
  const int col = lane & 15;
  const int n = n0 + wn * 16 + col;
  const float vbr = br[n], vbz = bz[n], vbn = bn[n];
#pragma unroll
  for (int i = 0; i < 8; ++i) {
    const int mbase = m0 + i * 16 + quad * 4;
#pragma unroll
    for (int r = 0; r < 4; ++r) {
      const int m = mbase + r;
      const float gr = acc_r[i][r] + vbr;
      const float gz = acc_z[i][r] + vbz;
      const float rg = 1.0f / (1.0f + __expf(-gr));
      const float zg = 1.0f / (1.0f + __expf(-gz));
      const float gn = acc_in[i][r] + rg * acc_hn[i][r] + vbn;
      const float e2 = __expf(2.0f * gn);
      const float ntv = 1.0f - 2.0f / (e2 + 1.0f);
      const float hp = h[m * 512 + n];
      out[m * 512 + n] = (1.0f - zg) * ntv + zg * hp;
    }
  }
}

extern "C" void kernel_launch(void* const* d_in, const int* in_sizes, int n_in,
                              void* d_out, int out_size, void* d_ws, size_t ws_size,
                              hipStream_t stream) {
  const float* x   = (const float*)d_in[0];
  const float* h   = (const float*)d_in[1];
  const float* Wir = (const float*)d_in[2];
  const float* Whr = (const float*)d_in[3];
  const float* br  = (const float*)d_in[4];
  const float* Wiz = (const float*)d_in[5];
  const float* Whz = (const float*)d_in[6];
  const float* bz  = (const float*)d_in[7];
  const float* Win = (const float*)d_in[8];
  const float* Whn = (const float*)d_in[9];
  const float* bn  = (const float*)d_in[10];
  float* out = (float*)d_out;
  _Float16* wperm = (_Float16*)d_ws;

  const size_t need_bytes = (APERM_OFF + APERM_HALFS) * 2;  // ~73.4 MB
  if (ws_size >= need_bytes) {
    prep<<<1792, 256, 0, stream>>>(x, h, Wir, Whr, Wiz, Whz, Win, Whn, wperm);
    gru_fused2<<<1024, 256, 0, stream>>>(h, wperm, br, bz, bn, out);
  } else {
    permute_w_old<<<768, 256, 0, stream>>>(Wir, Whr, Wiz, Whz, Win, Whn, wperm);
    gru_fused_fb<<<1024, 256, 0, stream>>>(x, h, wperm, br, bz, bn, out);
  }
}

// Round 10
// 257.260 us; speedup vs baseline: 1.1592x; 1.0048x over previous
//
#include <hip/hip_runtime.h>
#include <hip/hip_fp16.h>

typedef _Float16 half8 __attribute__((ext_vector_type(8)));
typedef float floatx4 __attribute__((ext_vector_type(4)));

#define AS1 __attribute__((address_space(1)))
#define AS3 __attribute__((address_space(3)))

// workspace layout (halfs):
//   [0, WLO_OFF)            W hi fragments, strided layout:
//       ((w*8+nt)*16+kt)*2048 + wv*512 + lane*8   (w = matrix 0..5)
//   [WLO_OFF, 2*WLO_OFF)    W lo fragments (same indexing)
//   [APERM_OFF, ...)        x/h hi/lo fragment-ordered (per mt,kt:
//       Xh|Xl|Hh|Hl x 4096 halfs)
// NOTE: R7's contiguous W layout measured SLOWER (148.5 vs 137 us) than this
// strided one (L2 hotspotting on the shared 24KB chunk) — keep strided.
#define WLO_OFF (6 * 512 * 512)
#define WMAT_STRIDE ((size_t)(8 * 16 * 2048))
#define APERM_OFF ((size_t)(2 * WLO_OFF))
#define APERM_HALFS ((size_t)128 * 16 * 4 * 4096)

__device__ __forceinline__ void async_lds16(const void* g, void* l) {
  __builtin_amdgcn_global_load_lds((const AS1 void*)g, (AS3 void*)l, 16, 0, 0);
}

// ---------------------------------------------------------------------------
// prep: blocks 0..1023 -> x/h fp32 to fragment-ordered f16 hi/lo (aperm).
//   Block = (mt, kt-pair); TWO 64-row passes with a 34.8 KB slab ->
//   4 blocks/CU (was 2 with the 70 KB slab) for better latency hiding.
//   Reads stay fully coalesced (256B dense per row).
// blocks 1024..1791 -> W permute into the STRIDED (R4-verified) layout.
// ---------------------------------------------------------------------------
__global__ __launch_bounds__(256) void prep(
    const float* __restrict__ x, const float* __restrict__ h,
    const float* __restrict__ Wir, const float* __restrict__ Whr,
    const float* __restrict__ Wiz, const float* __restrict__ Whz,
    const float* __restrict__ Win, const float* __restrict__ Whn,
    _Float16* __restrict__ wperm) {
  __shared__ __align__(16) float xt[64 * 68];  // 17.4 KB (pad 68)
  __shared__ __align__(16) float ht[64 * 68];
  const int b = blockIdx.x;
  const int t = threadIdx.x;

  if (b >= 1024) {
    // ---- W permute (strided layout); 32x68 tile fits in xt ----
    const int b2 = b - 1024;
    const int w = b2 >> 7;
    const int rem = b2 & 127;
    const int ki = rem >> 3;
    const int nt = rem & 7;
    const float* W = (w == 0) ? Wir : (w == 1) ? Whr : (w == 2) ? Wiz
                   : (w == 3) ? Whz : (w == 4) ? Win : Whn;
    const int k0 = ki * 32, n0 = nt * 64;
    const int kk = t >> 3;
    const int nn = (t & 7) * 8;
    const float* src = W + (k0 + kk) * 512 + n0 + nn;
    float4 f0 = *(const float4*)(src);
    float4 f1 = *(const float4*)(src + 4);
    float* drow = xt + kk * 68 + nn;
    *(float4*)(drow) = f0;
    *(float4*)(drow + 4) = f1;
    __syncthreads();
    const int u = t >> 6, l = t & 63;
    const int nloc = 16 * u + (l & 15);
    const int kbase = 8 * (l >> 4);
    half8 vh2, vl2;
#pragma unroll
    for (int j = 0; j < 8; ++j) {
      float f = xt[(kbase + j) * 68 + nloc];
      _Float16 hi = (_Float16)f;
      _Float16 lo = (_Float16)(f - (float)hi);
      vh2[j] = hi;
      vl2[j] = lo;
    }
    const size_t off = ((size_t)((w * 8 + nt) * 16 + ki)) * 2048 + t * 8;
    *(half8*)(wperm + off) = vh2;
    *(half8*)(wperm + WLO_OFF + off) = vl2;
    return;
  }

  // ---- x/h -> aperm (kt-pair, two 64-row passes) ----
  const int mt = b >> 3;        // 0..127
  const int kp = b & 7;         // kt pair: kt = kp*2 + ii
  _Float16* dstbase = wperm + APERM_OFF + ((size_t)(mt * 16)) * 16384;

#pragma unroll
  for (int p = 0; p < 2; ++p) {
    // read rows 64p..64p+63, 64 cols: thread t -> local row t>>2,
    // cols (t&3)*16..+15 (4 lanes x 64B = dense 256B row segment)
    {
      const int r = t >> 2;
      const int c = (t & 3) * 16;
      const float* sx = x + ((size_t)(mt * 128 + 64 * p + r)) * 512 + kp * 64 + c;
      const float* sh = h + ((size_t)(mt * 128 + 64 * p + r)) * 512 + kp * 64 + c;
      float4 a0 = *(const float4*)(sx);
      float4 a1 = *(const float4*)(sx + 4);
      float4 a2 = *(const float4*)(sx + 8);
      float4 a3 = *(const float4*)(sx + 12);
      float4 b0 = *(const float4*)(sh);
      float4 b1 = *(const float4*)(sh + 4);
      float4 b2 = *(const float4*)(sh + 8);
      float4 b3 = *(const float4*)(sh + 12);
      float* dx = xt + r * 68 + c;
      float* dh = ht + r * 68 + c;
      *(float4*)(dx) = a0; *(float4*)(dx + 4) = a1;
      *(float4*)(dx + 8) = a2; *(float4*)(dx + 12) = a3;
      *(float4*)(dh) = b0; *(float4*)(dh + 4) = b1;
      *(float4*)(dh + 8) = b2; *(float4*)(dh + 12) = b3;
    }
    __syncthreads();

    // emit chunk cc = p*256 + t of both kt tiles (local row = cc's m - 64p)
    const int mloc = 16 * (t >> 6) + (t & 15);
    const int kA = 8 * ((t >> 4) & 3);
    const int cc = p * 256 + t;
#pragma unroll
    for (int ii = 0; ii < 2; ++ii) {
      const int cb = ii * 32;
      _Float16* dst = dstbase + (size_t)(kp * 2 + ii) * 16384;
      half8 xh, xl, hh, hl;
#pragma unroll
      for (int j = 0; j < 8; ++j) {
        float fx = xt[mloc * 68 + cb + kA + j];
        float fh = ht[mloc * 68 + cb + kA + j];
        _Float16 a = (_Float16)fx;
        xh[j] = a; xl[j] = (_Float16)(fx - (float)a);
        _Float16 bb = (_Float16)fh;
        hh[j] = bb; hl[j] = (_Float16)(fh - (float)bb);
      }
      *(half8*)(dst + 0 * 4096 + cc * 8) = xh;
      *(half8*)(dst + 1 * 4096 + cc * 8) = xl;
      *(half8*)(dst + 2 * 4096 + cc * 8) = hh;
      *(half8*)(dst + 3 * 4096 + cc * 8) = hl;
    }
    __syncthreads();  // slab consumed before pass-1 overwrite
  }
}

// ---------------------------------------------------------------------------
// gru_fused2: R4/R9 structure (best measured: 134.6 us, MfmaUtil 52.5%).
//   THIS ROUND'S ONE CHANGE — block->XCD mapping flipped to nt = xcd:
//   per-XCD W working set becomes 786 KB (L2-RESIDENT) so the 12 W loads
//   on every k-step's critical path are L2 hits instead of L3 round-trips.
//   The aperm DMA (latency-tolerant: drained one k-step later at the
//   barrier) absorbs the L3 latency instead. [R4-R9 had mt-pinning: W =
//   6.3 MB/XCD > 4 MB L2 -> critical-path L3 misses every k-step.]
// ---------------------------------------------------------------------------
__global__ __launch_bounds__(256, 2) void gru_fused2(
    const float* __restrict__ h, const _Float16* __restrict__ wperm,
    const float* __restrict__ br, const float* __restrict__ bz,
    const float* __restrict__ bn, float* __restrict__ out) {
  __shared__ __align__(16) _Float16 ldsA[2 * 4 * 4096];  // 64 KB dbuf

  const int t = threadIdx.x;
  const int lane = t & 63;
  const int wv = t >> 6;
  const int bid = blockIdx.x;
  const int nt = bid & 7;     // nt == XCD -> this XCD's W slice is L2-resident
  const int mt = bid >> 3;    // aperm slice streams via L3 (DMA hides latency)
  const int m0 = mt * 128;
  const int n0 = nt * 64;
  const _Float16* wlo = wperm + WLO_OFF;
  const _Float16* aperm = wperm + APERM_OFF + (size_t)mt * 16 * 16384;

  floatx4 acc_r[8] = {};
  floatx4 acc_z[8] = {};
  floatx4 acc_in[8] = {};
  floatx4 acc_hn[8] = {};

  {
    const _Float16* asrc = aperm + wv * 4096 + lane * 8;
    _Float16* adst = ldsA + wv * 4096;
#pragma unroll
    for (int q = 0; q < 8; ++q) async_lds16(asrc + q * 512, adst + q * 512);
  }
  __syncthreads();

#pragma unroll 2
  for (int kt = 0; kt < 16; ++kt) {
    const _Float16* A = ldsA + (kt & 1) * 16384;

    const size_t tb = ((size_t)(nt * 16 + kt)) * 2048 + wv * 512 + lane * 8;
    half8 bh_ir = *(const half8*)(wperm + tb + 0 * WMAT_STRIDE);
    half8 bh_hr = *(const half8*)(wperm + tb + 1 * WMAT_STRIDE);
    half8 bh_iz = *(const half8*)(wperm + tb + 2 * WMAT_STRIDE);
    half8 bh_hz = *(const half8*)(wperm + tb + 3 * WMAT_STRIDE);
    half8 bh_in = *(const half8*)(wperm + tb + 4 * WMAT_STRIDE);
    half8 bh_hn = *(const half8*)(wperm + tb + 5 * WMAT_STRIDE);
    half8 bl_ir = *(const half8*)(wlo + tb + 0 * WMAT_STRIDE);
    half8 bl_hr = *(const half8*)(wlo + tb + 1 * WMAT_STRIDE);
    half8 bl_iz = *(const half8*)(wlo + tb + 2 * WMAT_STRIDE);
    half8 bl_hz = *(const half8*)(wlo + tb + 3 * WMAT_STRIDE);
    half8 bl_in = *(const half8*)(wlo + tb + 4 * WMAT_STRIDE);
    half8 bl_hn = *(const half8*)(wlo + tb + 5 * WMAT_STRIDE);
    __builtin_amdgcn_sched_barrier(0);

    if (kt < 15) {
      const _Float16* asrc =
          aperm + (size_t)(kt + 1) * 16384 + wv * 4096 + lane * 8;
      _Float16* adst = ldsA + ((kt & 1) ^ 1) * 16384 + wv * 4096;
#pragma unroll
      for (int q = 0; q < 8; ++q) async_lds16(asrc + q * 512, adst + q * 512);
    }
    __builtin_amdgcn_sched_barrier(0);

    __builtin_amdgcn_s_setprio(1);
#pragma unroll
    for (int i = 0; i < 8; ++i) {
      const int ao = (i * 64 + lane) * 8;
      half8 axh = *(const half8*)(A + 0 * 4096 + ao);
      half8 axl = *(const half8*)(A + 1 * 4096 + ao);
      half8 ahh = *(const half8*)(A + 2 * 4096 + ao);
      half8 ahl = *(const half8*)(A + 3 * 4096 + ao);
      acc_r[i]  = __builtin_amdgcn_mfma_f32_16x16x32_f16(axh, bh_ir, acc_r[i], 0, 0, 0);
      acc_r[i]  = __builtin_amdgcn_mfma_f32_16x16x32_f16(ahh, bh_hr, acc_r[i], 0, 0, 0);
      acc_z[i]  = __builtin_amdgcn_mfma_f32_16x16x32_f16(axh, bh_iz, acc_z[i], 0, 0, 0);
      acc_z[i]  = __builtin_amdgcn_mfma_f32_16x16x32_f16(ahh, bh_hz, acc_z[i], 0, 0, 0);
      acc_in[i] = __builtin_amdgcn_mfma_f32_16x16x32_f16(axh, bh_in, acc_in[i], 0, 0, 0);
      acc_hn[i] = __builtin_amdgcn_mfma_f32_16x16x32_f16(ahh, bh_hn, acc_hn[i], 0, 0, 0);
      acc_r[i]  = __builtin_amdgcn_mfma_f32_16x16x32_f16(axl, bh_ir, acc_r[i], 0, 0, 0);
      acc_r[i]  = __builtin_amdgcn_mfma_f32_16x16x32_f16(ahl, bh_hr, acc_r[i], 0, 0, 0);
      acc_z[i]  = __builtin_amdgcn_mfma_f32_16x16x32_f16(axl, bh_iz, acc_z[i], 0, 0, 0);
      acc_z[i]  = __builtin_amdgcn_mfma_f32_16x16x32_f16(ahl, bh_hz, acc_z[i], 0, 0, 0);
      acc_in[i] = __builtin_amdgcn_mfma_f32_16x16x32_f16(axl, bh_in, acc_in[i], 0, 0, 0);
      acc_hn[i] = __builtin_amdgcn_mfma_f32_16x16x32_f16(ahl, bh_hn, acc_hn[i], 0, 0, 0);
      acc_r[i]  = __builtin_amdgcn_mfma_f32_16x16x32_f16(axh, bl_ir, acc_r[i], 0, 0, 0);
      acc_r[i]  = __builtin_amdgcn_mfma_f32_16x16x32_f16(ahh, bl_hr, acc_r[i], 0, 0, 0);
      acc_z[i]  = __builtin_amdgcn_mfma_f32_16x16x32_f16(axh, bl_iz, acc_z[i], 0, 0, 0);
      acc_z[i]  = __builtin_amdgcn_mfma_f32_16x16x32_f16(ahh, bl_hz, acc_z[i], 0, 0, 0);
      acc_in[i] = __builtin_amdgcn_mfma_f32_16x16x32_f16(axh, bl_in, acc_in[i], 0, 0, 0);
      acc_hn[i] = __builtin_amdgcn_mfma_f32_16x16x32_f16(ahh, bl_hn, acc_hn[i], 0, 0, 0);
    }
    __builtin_amdgcn_s_setprio(0);

    __syncthreads();  // buf[cur] consumed; buf[cur^1] DMA drained + visible
  }

  // --- epilogue: gates + h_new. C/D layout: col = lane&15, row = quad*4+reg
  const int quad = lane >> 4;
  const int col = lane & 15;
  const int n = n0 + wv * 16 + col;
  const float vbr = br[n], vbz = bz[n], vbn = bn[n];
#pragma unroll
  for (int i = 0; i < 8; ++i) {
    const int mbase = m0 + i * 16 + quad * 4;
#pragma unroll
    for (int r = 0; r < 4; ++r) {
      const int m = mbase + r;
      const float gr = acc_r[i][r] + vbr;
      const float gz = acc_z[i][r] + vbz;
      const float rg = 1.0f / (1.0f + __expf(-gr));
      const float zg = 1.0f / (1.0f + __expf(-gz));
      const float gn = acc_in[i][r] + rg * acc_hn[i][r] + vbn;
      const float e2 = __expf(2.0f * gn);          // inf-safe: tanh->+/-1
      const float ntv = 1.0f - 2.0f / (e2 + 1.0f);
      const float hp = h[m * 512 + n];
      out[m * 512 + n] = (1.0f - zg) * ntv + zg * hp;
    }
  }
}

// ---------------------------------------------------------------------------
// Fallback pair (ws too small for aperm): W permute + R3-style kernel that
// splits x/h in-kernel (no aperm needed).
// ---------------------------------------------------------------------------
__global__ __launch_bounds__(256) void permute_w_old(
    const float* __restrict__ Wir, const float* __restrict__ Whr,
    const float* __restrict__ Wiz, const float* __restrict__ Whz,
    const float* __restrict__ Win, const float* __restrict__ Whn,
    _Float16* __restrict__ wperm) {
  __shared__ __align__(16) float tile[32 * 68];
  const int b = blockIdx.x;
  const int t = threadIdx.x;
  const int w = b >> 7;
  const int rem = b & 127;
  const int ki = rem >> 3;
  const int nt = rem & 7;
  const float* W = (w == 0) ? Wir : (w == 1) ? Whr : (w == 2) ? Wiz
                 : (w == 3) ? Whz : (w == 4) ? Win : Whn;
  const int k0 = ki * 32, n0 = nt * 64;
  const int kk = t >> 3;
  const int nn = (t & 7) * 8;
  const float* src = W + (k0 + kk) * 512 + n0 + nn;
  float4 f0 = *(const float4*)(src);
  float4 f1 = *(const float4*)(src + 4);
  float* drow = tile + kk * 68 + nn;
  *(float4*)(drow) = f0;
  *(float4*)(drow + 4) = f1;
  __syncthreads();
  const int u = t >> 6, l = t & 63;
  const int nloc = 16 * u + (l & 15);
  const int kbase = 8 * (l >> 4);
  half8 vh2, vl2;
#pragma unroll
  for (int j = 0; j < 8; ++j) {
    float f = tile[(kbase + j) * 68 + nloc];
    _Float16 hi = (_Float16)f;
    _Float16 lo = (_Float16)(f - (float)hi);
    vh2[j] = hi;
    vl2[j] = lo;
  }
  const size_t off = ((size_t)((w * 8 + nt) * 16 + ki)) * 2048 + t * 8;
  *(half8*)(wperm + off) = vh2;
  *(half8*)(wperm + WLO_OFF + off) = vl2;
}

__global__ __launch_bounds__(256, 2) void gru_fused_fb(
    const float* __restrict__ x, const float* __restrict__ h,
    const _Float16* __restrict__ wperm,
    const float* __restrict__ br, const float* __restrict__ bz,
    const float* __restrict__ bn, float* __restrict__ out) {
  __shared__ __align__(16) _Float16 ldsA[2 * 4 * 4096];
  const int t = threadIdx.x;
  const int lane = t & 63;
  const int wn = t >> 6;
  const int bid = blockIdx.x;
  const int nt = bid & 7;
  const int mt = bid >> 3;
  const int m0 = mt * 128;
  const int n0 = nt * 64;
  const _Float16* wlo = wperm + WLO_OFF;

  floatx4 acc_r[8] = {};
  floatx4 acc_z[8] = {};
  floatx4 acc_in[8] = {};
  floatx4 acc_hn[8] = {};

  const int mA = 16 * (t >> 6) + (t & 15);
  const int kA = 8 * ((t >> 4) & 3);
  const float* px0 = x + (m0 + mA) * 512 + kA;
  const float* ph0 = h + (m0 + mA) * 512 + kA;
  const float* px1 = px0 + 64 * 512;
  const float* ph1 = ph0 + 64 * 512;
  const int c0 = t, c1 = t + 256;

  {
    float v[4][8];
    *(float4*)&v[0][0] = *(const float4*)(px0); *(float4*)&v[0][4] = *(const float4*)(px0 + 4);
    *(float4*)&v[1][0] = *(const float4*)(px1); *(float4*)&v[1][4] = *(const float4*)(px1 + 4);
    *(float4*)&v[2][0] = *(const float4*)(ph0); *(float4*)&v[2][4] = *(const float4*)(ph0 + 4);
    *(float4*)&v[3][0] = *(const float4*)(ph1); *(float4*)&v[3][4] = *(const float4*)(ph1 + 4);
#pragma unroll
    for (int g = 0; g < 4; ++g) {
      half8 hi, lo;
#pragma unroll
      for (int j = 0; j < 8; ++j) {
        _Float16 a = (_Float16)v[g][j];
        hi[j] = a;
        lo[j] = (_Float16)(v[g][j] - (float)a);
      }
      const int c = (g & 1) ? c1 : c0;
      const int part = (g >> 1) * 2;
      *(half8*)(ldsA + (part + 0) * 4096 + c * 8) = hi;
      *(half8*)(ldsA + (part + 1) * 4096 + c * 8) = lo;
    }
  }
  __syncthreads();

#pragma unroll 2
  for (int kt = 0; kt < 16; ++kt) {
    const _Float16* A = ldsA + (kt & 1) * 16384;
    const size_t tb = ((size_t)(nt * 16 + kt)) * 2048 + wn * 512 + lane * 8;
    half8 bh_ir = *(const half8*)(wperm + tb + 0 * WMAT_STRIDE);
    half8 bh_hr = *(const half8*)(wperm + tb + 1 * WMAT_STRIDE);
    half8 bh_iz = *(const half8*)(wperm + tb + 2 * WMAT_STRIDE);
    half8 bh_hz = *(const half8*)(wperm + tb + 3 * WMAT_STRIDE);
    half8 bh_in = *(const half8*)(wperm + tb + 4 * WMAT_STRIDE);
    half8 bh_hn = *(const half8*)(wperm + tb + 5 * WMAT_STRIDE);
    half8 bl_ir = *(const half8*)(wlo + tb + 0 * WMAT_STRIDE);
    half8 bl_hr = *(const half8*)(wlo + tb + 1 * WMAT_STRIDE);
    half8 bl_iz = *(const half8*)(wlo + tb + 2 * WMAT_STRIDE);
    half8 bl_hz = *(const half8*)(wlo + tb + 3 * WMAT_STRIDE);
    half8 bl_in = *(const half8*)(wlo + tb + 4 * WMAT_STRIDE);
    half8 bl_hn = *(const half8*)(wlo + tb + 5 * WMAT_STRIDE);
    __builtin_amdgcn_sched_barrier(0);

    float v[4][8];
    if (kt < 15) {
      const int k0 = (kt + 1) * 32;
      *(float4*)&v[0][0] = *(const float4*)(px0 + k0); *(float4*)&v[0][4] = *(const float4*)(px0 + k0 + 4);
      *(float4*)&v[1][0] = *(const float4*)(px1 + k0); *(float4*)&v[1][4] = *(const float4*)(px1 + k0 + 4);
      *(float4*)&v[2][0] = *(const float4*)(ph0 + k0); *(float4*)&v[2][4] = *(const float4*)(ph0 + k0 + 4);
      *(float4*)&v[3][0] = *(const float4*)(ph1 + k0); *(float4*)&v[3][4] = *(const float4*)(ph1 + k0 + 4);
    }
    __builtin_amdgcn_sched_barrier(0);

    __builtin_amdgcn_s_setprio(1);
#pragma unroll
    for (int i = 0; i < 8; ++i) {
      const int ao = (i * 64 + lane) * 8;
      half8 axh = *(const half8*)(A + 0 * 4096 + ao);
      half8 axl = *(const half8*)(A + 1 * 4096 + ao);
      half8 ahh = *(const half8*)(A + 2 * 4096 + ao);
      half8 ahl = *(const half8*)(A + 3 * 4096 + ao);
      acc_r[i]  = __builtin_amdgcn_mfma_f32_16x16x32_f16(axh, bh_ir, acc_r[i], 0, 0, 0);
      acc_r[i]  = __builtin_amdgcn_mfma_f32_16x16x32_f16(ahh, bh_hr, acc_r[i], 0, 0, 0);
      acc_z[i]  = __builtin_amdgcn_mfma_f32_16x16x32_f16(axh, bh_iz, acc_z[i], 0, 0, 0);
      acc_z[i]  = __builtin_amdgcn_mfma_f32_16x16x32_f16(ahh, bh_hz, acc_z[i], 0, 0, 0);
      acc_in[i] = __builtin_amdgcn_mfma_f32_16x16x32_f16(axh, bh_in, acc_in[i], 0, 0, 0);
      acc_hn[i] = __builtin_amdgcn_mfma_f32_16x16x32_f16(ahh, bh_hn, acc_hn[i], 0, 0, 0);
      acc_r[i]  = __builtin_amdgcn_mfma_f32_16x16x32_f16(axl, bh_ir, acc_r[i], 0, 0, 0);
      acc_r[i]  = __builtin_amdgcn_mfma_f32_16x16x32_f16(ahl, bh_hr, acc_r[i], 0, 0, 0);
      acc_z[i]  = __builtin_amdgcn_mfma_f32_16x16x32_f16(axl, bh_iz, acc_z[i], 0, 0, 0);
      acc_z[i]  = __builtin_amdgcn_mfma_f32_16x16x32_f16(ahl, bh_hz, acc_z[i], 0, 0, 0);
      acc_in[i] = __builtin_amdgcn_mfma_f32_16x16x32_f16(axl, bh_in, acc_in[i], 0, 0, 0);
      acc_hn[i] = __builtin_amdgcn_mfma_f32_16x16x32_f16(ahl, bh_hn, acc_hn[i], 0, 0, 0);
      acc_r[i]  = __builtin_amdgcn_mfma_f32_16x16x32_f16(axh, bl_ir, acc_r[i], 0, 0, 0);
      acc_r[i]  = __builtin_amdgcn_mfma_f32_16x16x32_f16(ahh, bl_hr, acc_r[i], 0, 0, 0);
      acc_z[i]  = __builtin_amdgcn_mfma_f32_16x16x32_f16(axh, bl_iz, acc_z[i], 0, 0, 0);
      acc_z[i]  = __builtin_amdgcn_mfma_f32_16x16x32_f16(ahh, bl_hz, acc_z[i], 0, 0, 0);
      acc_in[i] = __builtin_amdgcn_mfma_f32_16x16x32_f16(axh, bl_in, acc_in[i], 0, 0, 0);
      acc_hn[i] = __builtin_amdgcn_mfma_f32_16x16x32_f16(ahh, bl_hn, acc_hn[i], 0, 0, 0);
    }
    __builtin_amdgcn_s_setprio(0);

    if (kt < 15) {
      _Float16* base = ldsA + ((kt & 1) ^ 1) * 16384;
#pragma unroll
      for (int g = 0; g < 4; ++g) {
        half8 hi, lo;
#pragma unroll
        for (int j = 0; j < 8; ++j) {
          _Float16 a = (_Float16)v[g][j];
          hi[j] = a;
          lo[j] = (_Float16)(v[g][j] - (float)a);
        }
        const int c = (g & 1) ? c1 : c0;
        const int part = (g >> 1) * 2;
        *(half8*)(base + (part + 0) * 4096 + c * 8) = hi;
        *(half8*)(base + (part + 1) * 4096 + c * 8) = lo;
      }
    }
    __syncthreads();
  }

  const int quad = lane >> 4;
  const int col = lane & 15;
  const int n = n0 + wn * 16 + col;
  const float vbr = br[n], vbz = bz[n], vbn = bn[n];
#pragma unroll
  for (int i = 0; i < 8; ++i) {
    const int mbase = m0 + i * 16 + quad * 4;
#pragma unroll
    for (int r = 0; r < 4; ++r) {
      const int m = mbase + r;
      const float gr = acc_r[i][r] + vbr;
      const float gz = acc_z[i][r] + vbz;
      const float rg = 1.0f / (1.0f + __expf(-gr));
      const float zg = 1.0f / (1.0f + __expf(-gz));
      const float gn = acc_in[i][r] + rg * acc_hn[i][r] + vbn;
      const float e2 = __expf(2.0f * gn);
      const float ntv = 1.0f - 2.0f / (e2 + 1.0f);
      const float hp = h[m * 512 + n];
      out[m * 512 + n] = (1.0f - zg) * ntv + zg * hp;
    }
  }
}

extern "C" void kernel_launch(void* const* d_in, const int* in_sizes, int n_in,
                              void* d_out, int out_size, void* d_ws, size_t ws_size,
                              hipStream_t stream) {
  const float* x   = (const float*)d_in[0];
  const float* h   = (const float*)d_in[1];
  const float* Wir = (const float*)d_in[2];
  const float* Whr = (const float*)d_in[3];
  const float* br  = (const float*)d_in[4];
  const float* Wiz = (const float*)d_in[5];
  const float* Whz = (const float*)d_in[6];
  const float* bz  = (const float*)d_in[7];
  const float* Win = (const float*)d_in[8];
  const float* Whn = (const float*)d_in[9];
  const float* bn  = (const float*)d_in[10];
  float* out = (float*)d_out;
  _Float16* wperm = (_Float16*)d_ws;

  const size_t need_bytes = (APERM_OFF + APERM_HALFS) * 2;  // ~73.4 MB
  if (ws_size >= need_bytes) {
    prep<<<1792, 256, 0, stream>>>(x, h, Wir, Whr, Wiz, Whz, Win, Whn, wperm);
    gru_fused2<<<1024, 256, 0, stream>>>(h, wperm, br, bz, bn, out);
  } else {
    permute_w_old<<<768, 256, 0, stream>>>(Wir, Whr, Wiz, Whz, Win, Whn, wperm);
    gru_fused_fb<<<1024, 256, 0, stream>>>(x, h, wperm, br, bz, bn, out);
  }
}